// Round 7
// baseline (358.431 us; speedup 1.0000x reference)
//
#include <hip/hip_runtime.h>
#include <math.h>

#define NWTOK 343
#define NTOK 117649
#define QSCALE 0.510069734f   // (1/sqrt(8)) * log2(e): folds softmax scale + exp2 conversion
#define LOG2E 1.4426950408889634f
#define QPLANE 1372   // u32 per (window,head) plane of f16 rows: 343*8*2B/4
#define OPLANE 2744   // f32 per (window,head) plane of o

typedef unsigned int u32;
typedef __fp16 h2 __attribute__((ext_vector_type(2)));

__device__ __forceinline__ float fdot2u(u32 a, u32 b, float c) {
#if __has_builtin(__builtin_amdgcn_fdot2)
    return __builtin_amdgcn_fdot2(__builtin_bit_cast(h2, a), __builtin_bit_cast(h2, b), c, false);
#else
    h2 ha = __builtin_bit_cast(h2, a), hb = __builtin_bit_cast(h2, b);
    return fmaf((float)ha.y, (float)hb.y, fmaf((float)ha.x, (float)hb.x, c));
#endif
}
__device__ __forceinline__ u32 packh2(float a, float b) {
    h2 h = __builtin_amdgcn_cvt_pkrtz(a, b);
    return __builtin_bit_cast(u32, h);
}
__device__ __forceinline__ float2 unpackh2(u32 u) {
    h2 h = __builtin_bit_cast(h2, u);
    return make_float2((float)h.x, (float)h.y);
}
__device__ __forceinline__ float fast_exp2(float x) {
#if __has_builtin(__builtin_amdgcn_exp2f)
    return __builtin_amdgcn_exp2f(x);
#else
    return exp2f(x);
#endif
}

// Inline exact-GELU via Abramowitz-Stegun 7.1.26 erf (max abs err 1.5e-7).
__device__ __forceinline__ float gelu_exact(float x) {
    const float z = x * 0.70710678118654752f;
    const float az = fabsf(z);
    const float t = __builtin_amdgcn_rcpf(fmaf(0.3275911f, az, 1.0f));
    float y = fmaf(t, 1.061405429f, -1.453152027f);
    y = fmaf(t, y, 1.421413741f);
    y = fmaf(t, y, -0.284496736f);
    y = fmaf(t, y, 0.254829592f);
    y *= t;
    const float one_m_erf = y * __expf(-az * az);
    const float erf_az = 1.0f - one_m_erf;
    const float erf_z = (z < 0.f) ? -erf_az : erf_az;
    return 0.5f * x * (1.0f + erf_z);
}

__device__ __forceinline__ void store_f16_row(u32* base, int t, const float* v8) {
    uint4 u;
    u.x = packh2(v8[0], v8[1]); u.y = packh2(v8[2], v8[3]);
    u.z = packh2(v8[4], v8[5]); u.w = packh2(v8[6], v8[7]);
    *(uint4*)(base + t * 4) = u;
}

// ---------------- K0: patch embed + LN + LN1 + QKV(block 0) ----------------
__global__ __launch_bounds__(256, 2) void k0_patch_qkv(
    const float* __restrict__ x,
    const float* __restrict__ pe_w,
    const float* __restrict__ pe_bias,
    const float* __restrict__ pe_g,
    const float* __restrict__ pe_b,
    const float* __restrict__ n1_g,
    const float* __restrict__ n1_b,
    const float* __restrict__ qkv_w,
    float* __restrict__ xe,
    u32* __restrict__ qg,
    u32* __restrict__ kg,
    u32* __restrict__ vg)
{
    __shared__ float w_s[128];
    __shared__ float pb_s[16], g_s[16], b_s[16], n1g_s[16], n1b_s[16];
    __shared__ float qkvw_s[768];
    const int tid = threadIdx.x;
    if (tid < 128) w_s[tid] = pe_w[tid];
    if (tid < 16) {
        pb_s[tid] = pe_bias[tid]; g_s[tid] = pe_g[tid]; b_s[tid] = pe_b[tid];
        n1g_s[tid] = n1_g[tid]; n1b_s[tid] = n1_b[tid];
    }
    for (int i = tid; i < 768; i += 256) qkvw_s[i] = qkv_w[i];
    __syncthreads();
    const int g = blockIdx.x * 256 + tid;
    if (g >= NTOK) return;
    const int z = g / 2401;
    const int r = g - z * 2401;
    const int y = r / 49;
    const int xx = r - y * 49;
    const float* bp = x + ((2 * z) * 98 + (2 * y)) * 98 + 2 * xx;
    float in[8];
    in[0] = bp[0];    in[1] = bp[1];
    in[2] = bp[98];   in[3] = bp[99];
    in[4] = bp[9604]; in[5] = bp[9605];
    in[6] = bp[9702]; in[7] = bp[9703];
    float v[16];
    float mu = 0.f;
    #pragma unroll
    for (int c = 0; c < 16; ++c) {
        float a = pb_s[c];
        #pragma unroll
        for (int k = 0; k < 8; ++k) a = fmaf(in[k], w_s[c * 8 + k], a);
        v[c] = a; mu += a;
    }
    mu *= 0.0625f;
    float var = 0.f;
    #pragma unroll
    for (int c = 0; c < 16; ++c) { float d = v[c] - mu; var = fmaf(d, d, var); }
    var *= 0.0625f;
    float rs = rsqrtf(var + 1e-5f);
    float o[16];
    #pragma unroll
    for (int c = 0; c < 16; ++c) o[c] = (v[c] - mu) * rs * g_s[c] + b_s[c];

    const int zw = z / 7, zi = z - zw * 7;
    const int yw = y / 7, yi = y - yw * 7;
    const int xw = xx / 7, xi = xx - xw * 7;
    const int w = (zw * 7 + yw) * 7 + xw;
    const int t = (zi * 7 + yi) * 7 + xi;
    const int widx = w * NWTOK + t;

    float4* dst = (float4*)(xe + (size_t)widx * 16);
    dst[0] = ((float4*)o)[0]; dst[1] = ((float4*)o)[1];
    dst[2] = ((float4*)o)[2]; dst[3] = ((float4*)o)[3];

    mu = 0.f;
    #pragma unroll
    for (int c = 0; c < 16; ++c) mu += o[c];
    mu *= 0.0625f;
    var = 0.f;
    #pragma unroll
    for (int c = 0; c < 16; ++c) { float d = o[c] - mu; var = fmaf(d, d, var); }
    var *= 0.0625f;
    rs = rsqrtf(var + 1e-5f);
    float yv[16];
    #pragma unroll
    for (int c = 0; c < 16; ++c) yv[c] = (o[c] - mu) * rs * n1g_s[c] + n1b_s[c];

    float tmp[16];
    #pragma unroll
    for (int rr = 0; rr < 16; ++rr) {
        float a = 0.f;
        #pragma unroll
        for (int c = 0; c < 16; ++c) a = fmaf(yv[c], qkvw_s[rr * 16 + c], a);
        tmp[rr] = a * QSCALE;
    }
    store_f16_row(qg + (size_t)(w * 2) * QPLANE, t, tmp);
    store_f16_row(qg + (size_t)(w * 2 + 1) * QPLANE, t, tmp + 8);
    #pragma unroll
    for (int rr = 0; rr < 16; ++rr) {
        float a = 0.f;
        #pragma unroll
        for (int c = 0; c < 16; ++c) a = fmaf(yv[c], qkvw_s[(16 + rr) * 16 + c], a);
        tmp[rr] = a;
    }
    store_f16_row(kg + (size_t)(w * 2) * QPLANE, t, tmp);
    store_f16_row(kg + (size_t)(w * 2 + 1) * QPLANE, t, tmp + 8);
    #pragma unroll
    for (int rr = 0; rr < 16; ++rr) {
        float a = 0.f;
        #pragma unroll
        for (int c = 0; c < 16; ++c) a = fmaf(yv[c], qkvw_s[(32 + rr) * 16 + c], a);
        tmp[rr] = a;
    }
    store_f16_row(vg + (size_t)(w * 2) * QPLANE, t, tmp);
    store_f16_row(vg + (size_t)(w * 2 + 1) * QPLANE, t, tmp + 8);
}

// ---- K_attn: WG per (window,head); 4 rows/thread; 4-way j-split; shfl merge ----
// tid = t*4 + qrt. Thread handles rows {t, t+86, t+172, t+258} for j in quarter
// qrt. A wave's lanes read only 4 distinct K/V rows per step (banks 0/24/16/8:
// conflict-free broadcast). Partials merged via __shfl_xor over qrt lanes.
__global__ __launch_bounds__(384, 4) void k_attn(
    const u32* __restrict__ qg,
    const u32* __restrict__ kg,
    const u32* __restrict__ vg,
    float* __restrict__ og,
    const float* __restrict__ rpb)
{
    __shared__ u32 ks4[NWTOK * 4];     // f16 K rows, 16B each
    __shared__ u32 vs4[NWTOK * 4];     // f16 V rows
    __shared__ float bias_s[2197];     // pre-scaled by log2(e)

    const int tid = threadIdx.x;
    const int wh = blockIdx.x;
    const int h = wh & 1;
    const size_t qpl = (size_t)wh * QPLANE;

    if (tid < NWTOK) {
        ((uint4*)ks4)[tid] = ((const uint4*)(kg + qpl))[tid];
        ((uint4*)vs4)[tid] = ((const uint4*)(vg + qpl))[tid];
    }
    for (int i = tid; i < 2197; i += 384) bias_s[i] = rpb[2 * i + h] * LOG2E;
    __syncthreads();

    if (tid >= 344) return;            // whole-quad groups drop out; shfl partners stay aligned

    const int qrt = tid & 3;
    const int t = tid >> 2;            // 0..85

    // 4 query rows: t, t+86, t+172, t+258 (t==85 -> row 343 invalid)
    u32 q[4][4];
    int base[4];
    #pragma unroll
    for (int r = 0; r < 4; ++r) {
        const int row = t + r * 86;
        if (row < NWTOK) {
            *(uint4*)q[r] = *(const uint4*)(qg + qpl + row * 4);
            const int z = row / 49, rr = row - z * 49, y = rr / 7, xx = rr - y * 7;
            base[r] = z * 169 + y * 13 + xx + 1098;
        } else {
            q[r][0] = q[r][1] = q[r][2] = q[r][3] = 0u;
            base[r] = 1098;
        }
    }

    float l[4];
    float acc[4][8];
    #pragma unroll
    for (int r = 0; r < 4; ++r) {
        l[r] = 0.f;
        #pragma unroll
        for (int d = 0; d < 8; ++d) acc[r][d] = 0.f;
    }

    const int n_iters = (qrt == 3) ? 85 : 86;
    int j = qrt * 86;
    int jz = j / 49;
    int jrm = j - jz * 49;
    int jy = jrm / 7;
    int jx = jrm - jy * 7;
    int joff = jz * 169 + jy * 13 + jx;

    #pragma unroll 2
    for (int n = 0; n < n_iters; ++n) {
        const uint4 kw = *(const uint4*)(ks4 + j * 4);
        const uint4 vw = *(const uint4*)(vs4 + j * 4);
        const float2 v01 = unpackh2(vw.x);
        const float2 v23 = unpackh2(vw.y);
        const float2 v45 = unpackh2(vw.z);
        const float2 v67 = unpackh2(vw.w);

        #pragma unroll
        for (int r = 0; r < 4; ++r) {
            float s = bias_s[base[r] - joff];
            s = fdot2u(q[r][0], kw.x, s);
            s = fdot2u(q[r][1], kw.y, s);
            s = fdot2u(q[r][2], kw.z, s);
            s = fdot2u(q[r][3], kw.w, s);
            const float p = fast_exp2(s);
            l[r] += p;
            acc[r][0] = fmaf(p, v01.x, acc[r][0]);
            acc[r][1] = fmaf(p, v01.y, acc[r][1]);
            acc[r][2] = fmaf(p, v23.x, acc[r][2]);
            acc[r][3] = fmaf(p, v23.y, acc[r][3]);
            acc[r][4] = fmaf(p, v45.x, acc[r][4]);
            acc[r][5] = fmaf(p, v45.y, acc[r][5]);
            acc[r][6] = fmaf(p, v67.x, acc[r][6]);
            acc[r][7] = fmaf(p, v67.y, acc[r][7]);
        }

        ++j; ++jx; ++joff;
        if (jx == 7) {
            jx = 0; joff += 6;
            ++jy;
            if (jy == 7) { jy = 0; joff += 78; }
        }
    }

    // butterfly merge across the 4 j-quarters (lanes differing in bits 0-1)
    #pragma unroll
    for (int r = 0; r < 4; ++r) {
        l[r] += __shfl_xor(l[r], 1);
        #pragma unroll
        for (int d = 0; d < 8; ++d) acc[r][d] += __shfl_xor(acc[r][d], 1);
        l[r] += __shfl_xor(l[r], 2);
        #pragma unroll
        for (int d = 0; d < 8; ++d) acc[r][d] += __shfl_xor(acc[r][d], 2);
    }

    if (qrt == 0) {
        float* op = og + (size_t)wh * OPLANE;
        #pragma unroll
        for (int r = 0; r < 4; ++r) {
            const int row = t + r * 86;
            if (row < NWTOK) {
                const float inv = 1.f / l[r];
                float o8[8];
                #pragma unroll
                for (int d = 0; d < 8; ++d) o8[d] = acc[r][d] * inv;
                *(float4*)(op + row * 8)     = *(float4*)(o8);
                *(float4*)(op + row * 8 + 4) = *(float4*)(o8 + 4);
            }
        }
    }
}

// ------- K_post: proj + residual + LN2 + MLP (+ next LN1+QKV or output) -------
__global__ __launch_bounds__(256, 2) void k_post(
    float* __restrict__ xe,
    const float* __restrict__ og,
    u32* __restrict__ qg,
    u32* __restrict__ kg,
    u32* __restrict__ vg,
    const float* __restrict__ proj_w,
    const float* __restrict__ proj_b,
    const float* __restrict__ n2_g,
    const float* __restrict__ n2_b,
    const float* __restrict__ fc1_w,
    const float* __restrict__ fc1_b,
    const float* __restrict__ fc2_w,
    const float* __restrict__ fc2_b,
    const float* __restrict__ n1_g_nx,
    const float* __restrict__ n1_b_nx,
    const float* __restrict__ qkv_w_nx,
    float* __restrict__ outp,
    const int last)
{
    __shared__ float projw_s[256];
    __shared__ float fc1w_s[1024];
    __shared__ float fc2w_s[1024];
    __shared__ float qkvw_s[768];
    __shared__ float projb_s[16], n2g_s[16], n2b_s[16], fc2b_s[16], n1g_s[16], n1b_s[16];
    __shared__ float fc1b_s[64];
    const int tid = threadIdx.x;
    if (tid < 256) projw_s[tid] = proj_w[tid];
    for (int i = tid; i < 1024; i += 256) { fc1w_s[i] = fc1_w[i]; fc2w_s[i] = fc2_w[i]; }
    for (int i = tid; i < 768; i += 256) qkvw_s[i] = qkv_w_nx[i];
    if (tid < 16) {
        projb_s[tid] = proj_b[tid];
        n2g_s[tid] = n2_g[tid]; n2b_s[tid] = n2_b[tid];
        fc2b_s[tid] = fc2_b[tid];
        n1g_s[tid] = n1_g_nx[tid]; n1b_s[tid] = n1_b_nx[tid];
    }
    if (tid < 64) fc1b_s[tid] = fc1_b[tid];
    __syncthreads();

    const int widx = blockIdx.x * 256 + tid;
    if (widx >= NTOK) return;
    const int w = widx / NWTOK;
    const int t = widx - w * NWTOK;

    float o[16];
    const float* o0 = og + (size_t)(w * 2) * OPLANE + t * 8;
    const float* o1 = og + (size_t)(w * 2 + 1) * OPLANE + t * 8;
    ((float4*)o)[0] = ((const float4*)o0)[0]; ((float4*)o)[1] = ((const float4*)o0)[1];
    ((float4*)o)[2] = ((const float4*)o1)[0]; ((float4*)o)[3] = ((const float4*)o1)[1];

    float xr[16];
    const float4* xs = (const float4*)(xe + (size_t)widx * 16);
    ((float4*)xr)[0] = xs[0]; ((float4*)xr)[1] = xs[1];
    ((float4*)xr)[2] = xs[2]; ((float4*)xr)[3] = xs[3];

    #pragma unroll
    for (int c = 0; c < 16; ++c) {
        float a = projb_s[c];
        #pragma unroll
        for (int cc = 0; cc < 16; ++cc) a = fmaf(o[cc], projw_s[c * 16 + cc], a);
        xr[c] += a;
    }

    float mu = 0.f;
    #pragma unroll
    for (int c = 0; c < 16; ++c) mu += xr[c];
    mu *= 0.0625f;
    float var = 0.f;
    #pragma unroll
    for (int c = 0; c < 16; ++c) { float d = xr[c] - mu; var = fmaf(d, d, var); }
    var *= 0.0625f;
    float rs = rsqrtf(var + 1e-5f);
    float zv[16];
    #pragma unroll
    for (int c = 0; c < 16; ++c) zv[c] = (xr[c] - mu) * rs * n2g_s[c] + n2b_s[c];

    float accm[16];
    #pragma unroll
    for (int c = 0; c < 16; ++c) accm[c] = fc2b_s[c];
    #pragma unroll
    for (int ch = 0; ch < 4; ++ch) {
        float hv[16];
        #pragma unroll
        for (int mm = 0; mm < 16; ++mm) {
            const int mi = ch * 16 + mm;
            float a = fc1b_s[mi];
            #pragma unroll
            for (int c = 0; c < 16; ++c) a = fmaf(zv[c], fc1w_s[mi * 16 + c], a);
            hv[mm] = gelu_exact(a);
        }
        #pragma unroll
        for (int c = 0; c < 16; ++c) {
            float a = accm[c];
            #pragma unroll
            for (int mm = 0; mm < 16; ++mm) a = fmaf(hv[mm], fc2w_s[c * 64 + ch * 16 + mm], a);
            accm[c] = a;
        }
    }
    #pragma unroll
    for (int c = 0; c < 16; ++c) xr[c] += accm[c];

    if (last) {
        const int wd = w / 49;
        const int wr2 = w - wd * 49;
        const int whh = wr2 / 7;
        const int www = wr2 - whh * 7;
        const int tz = t / 49;
        const int tr2 = t - tz * 49;
        const int ty = tr2 / 7;
        const int tx = tr2 - ty * 7;
        const int g = ((wd * 7 + tz) * 49 + (whh * 7 + ty)) * 49 + (www * 7 + tx);
        #pragma unroll
        for (int c = 0; c < 16; ++c) outp[(size_t)c * NTOK + g] = xr[c];
        return;
    }

    float4* dst = (float4*)(xe + (size_t)widx * 16);
    dst[0] = ((float4*)xr)[0]; dst[1] = ((float4*)xr)[1];
    dst[2] = ((float4*)xr)[2]; dst[3] = ((float4*)xr)[3];

    // LN1 + QKV for next block (f16 packed)
    mu = 0.f;
    #pragma unroll
    for (int c = 0; c < 16; ++c) mu += xr[c];
    mu *= 0.0625f;
    var = 0.f;
    #pragma unroll
    for (int c = 0; c < 16; ++c) { float d = xr[c] - mu; var = fmaf(d, d, var); }
    var *= 0.0625f;
    rs = rsqrtf(var + 1e-5f);
    float yv[16];
    #pragma unroll
    for (int c = 0; c < 16; ++c) yv[c] = (xr[c] - mu) * rs * n1g_s[c] + n1b_s[c];

    float tmp[16];
    #pragma unroll
    for (int rr = 0; rr < 16; ++rr) {
        float a = 0.f;
        #pragma unroll
        for (int c = 0; c < 16; ++c) a = fmaf(yv[c], qkvw_s[rr * 16 + c], a);
        tmp[rr] = a * QSCALE;
    }
    store_f16_row(qg + (size_t)(w * 2) * QPLANE, t, tmp);
    store_f16_row(qg + (size_t)(w * 2 + 1) * QPLANE, t, tmp + 8);
    #pragma unroll
    for (int rr = 0; rr < 16; ++rr) {
        float a = 0.f;
        #pragma unroll
        for (int c = 0; c < 16; ++c) a = fmaf(yv[c], qkvw_s[(16 + rr) * 16 + c], a);
        tmp[rr] = a;
    }
    store_f16_row(kg + (size_t)(w * 2) * QPLANE, t, tmp);
    store_f16_row(kg + (size_t)(w * 2 + 1) * QPLANE, t, tmp + 8);
    #pragma unroll
    for (int rr = 0; rr < 16; ++rr) {
        float a = 0.f;
        #pragma unroll
        for (int c = 0; c < 16; ++c) a = fmaf(yv[c], qkvw_s[(32 + rr) * 16 + c], a);
        tmp[rr] = a;
    }
    store_f16_row(vg + (size_t)(w * 2) * QPLANE, t, tmp);
    store_f16_row(vg + (size_t)(w * 2 + 1) * QPLANE, t, tmp + 8);
}

extern "C" void kernel_launch(void* const* d_in, const int* in_sizes, int n_in,
                              void* d_out, int out_size, void* d_ws, size_t ws_size,
                              hipStream_t stream) {
    const float* x       = (const float*)d_in[0];
    const float* pe_w    = (const float*)d_in[1];
    const float* pe_bias = (const float*)d_in[2];
    const float* pe_g    = (const float*)d_in[3];
    const float* pe_b    = (const float*)d_in[4];
    const float* n1_g    = (const float*)d_in[5];
    const float* n1_b    = (const float*)d_in[6];
    const float* qkv_w   = (const float*)d_in[7];
    const float* rpb     = (const float*)d_in[8];
    const float* proj_w  = (const float*)d_in[9];
    const float* proj_b  = (const float*)d_in[10];
    const float* n2_g    = (const float*)d_in[11];
    const float* n2_b    = (const float*)d_in[12];
    const float* fc1_w   = (const float*)d_in[13];
    const float* fc1_b   = (const float*)d_in[14];
    const float* fc2_w   = (const float*)d_in[15];
    const float* fc2_b   = (const float*)d_in[16];

    float* ws = (float*)d_ws;
    const size_t SEG = (size_t)NTOK * 16;     // 1,882,384 floats
    const size_t QSEG = (size_t)686 * QPLANE; // 941,192 u32
    float* xe = ws;
    u32* qg = (u32*)(ws + SEG);
    u32* kg = qg + QSEG;
    u32* vg = kg + QSEG;
    float* og = (float*)(vg + QSEG);          // 686*2744 f32
    float* out = (float*)d_out;

    k0_patch_qkv<<<(NTOK + 255) / 256, 256, 0, stream>>>(
        x, pe_w, pe_bias, pe_g, pe_b, n1_g, n1_b, qkv_w, xe, qg, kg, vg);

    for (int i = 0; i < 3; ++i) {
        const int last = (i == 2) ? 1 : 0;
        const int nx = last ? i : i + 1;
        k_attn<<<686, 384, 0, stream>>>(qg, kg, vg, og, rpb + (size_t)i * 2197 * 2);
        k_post<<<(NTOK + 255) / 256, 256, 0, stream>>>(
            xe, og, qg, kg, vg,
            proj_w + (size_t)i * 256, proj_b + (size_t)i * 16,
            n2_g + (size_t)i * 16, n2_b + (size_t)i * 16,
            fc1_w + (size_t)i * 1024, fc1_b + (size_t)i * 64,
            fc2_w + (size_t)i * 1024, fc2_b + (size_t)i * 16,
            n1_g + (size_t)nx * 16, n1_b + (size_t)nx * 16,
            qkv_w + (size_t)nx * 768,
            out, last);
    }
}

// Round 8
// 267.899 us; speedup vs baseline: 1.3379x; 1.3379x over previous
//
#include <hip/hip_runtime.h>
#include <math.h>

#define NWTOK 343
#define NTOK 117649
#define QSCALE 0.510069734f   // (1/sqrt(8)) * log2(e): folds softmax scale + exp2 conversion
#define LOG2E 1.4426950408889634f
#define QPLANE 1372   // u32 per (window,head) plane of f16 rows: 343*8*2B/4
#define OPLANE 2744   // f32 per (window,head) plane of o
#define NPAD 352      // 343 padded to 22*16

typedef unsigned int u32;
typedef __fp16 h2 __attribute__((ext_vector_type(2)));
typedef __fp16 h4 __attribute__((ext_vector_type(4)));
typedef float f32x4 __attribute__((ext_vector_type(4)));

__device__ __forceinline__ u32 packh2(float a, float b) {
    h2 h = __builtin_amdgcn_cvt_pkrtz(a, b);
    return __builtin_bit_cast(u32, h);
}
__device__ __forceinline__ float fast_exp2(float x) {
#if __has_builtin(__builtin_amdgcn_exp2f)
    return __builtin_amdgcn_exp2f(x);
#else
    return exp2f(x);
#endif
}

// Inline exact-GELU via Abramowitz-Stegun 7.1.26 erf (max abs err 1.5e-7).
__device__ __forceinline__ float gelu_exact(float x) {
    const float z = x * 0.70710678118654752f;
    const float az = fabsf(z);
    const float t = __builtin_amdgcn_rcpf(fmaf(0.3275911f, az, 1.0f));
    float y = fmaf(t, 1.061405429f, -1.453152027f);
    y = fmaf(t, y, 1.421413741f);
    y = fmaf(t, y, -0.284496736f);
    y = fmaf(t, y, 0.254829592f);
    y *= t;
    const float one_m_erf = y * __expf(-az * az);
    const float erf_az = 1.0f - one_m_erf;
    const float erf_z = (z < 0.f) ? -erf_az : erf_az;
    return 0.5f * x * (1.0f + erf_z);
}

__device__ __forceinline__ void store_f16_row(u32* base, int t, const float* v8) {
    uint4 u;
    u.x = packh2(v8[0], v8[1]); u.y = packh2(v8[2], v8[3]);
    u.z = packh2(v8[4], v8[5]); u.w = packh2(v8[6], v8[7]);
    *(uint4*)(base + t * 4) = u;
}

// ------- bias expand: bexp[blk*2+h][i(352)][j(352)] = rpb[rpi(i,j)][h]*log2e -------
// j>=343 -> -60 (exp2 -> ~0 kills key padding); i>=343 -> 0 (query padding, discarded)
__global__ __launch_bounds__(384) void k_bias_expand(
    const float* __restrict__ rpb,   // (3, 2197, 2)
    float* __restrict__ bexp)
{
    const int b = blockIdx.x;        // bh*352 + i
    const int bh = b / NPAD;
    const int i = b - bh * NPAD;
    const int blk = bh >> 1, h = bh & 1;
    const int j = threadIdx.x;
    if (j >= NPAD) return;
    float val;
    if (j >= NWTOK) {
        val = -60.f;
    } else if (i >= NWTOK) {
        val = 0.f;
    } else {
        const int iz = i / 49, ir = i - iz * 49, iy = ir / 7, ix = ir - iy * 7;
        const int jz = j / 49, jr = j - jz * 49, jy = jr / 7, jx = jr - jy * 7;
        const int idx = (iz - jz + 6) * 169 + (iy - jy + 6) * 13 + (ix - jx + 6);
        val = rpb[((size_t)blk * 2197 + idx) * 2 + h] * LOG2E;
    }
    bexp[((size_t)bh * NPAD + i) * NPAD + j] = val;
}

// ---------------- K0: patch embed + LN + LN1 + QKV(block 0) ----------------
__global__ __launch_bounds__(256, 2) void k0_patch_qkv(
    const float* __restrict__ x,
    const float* __restrict__ pe_w,
    const float* __restrict__ pe_bias,
    const float* __restrict__ pe_g,
    const float* __restrict__ pe_b,
    const float* __restrict__ n1_g,
    const float* __restrict__ n1_b,
    const float* __restrict__ qkv_w,
    float* __restrict__ xe,
    u32* __restrict__ qg,
    u32* __restrict__ kg,
    u32* __restrict__ vg)
{
    __shared__ float w_s[128];
    __shared__ float pb_s[16], g_s[16], b_s[16], n1g_s[16], n1b_s[16];
    __shared__ float qkvw_s[768];
    const int tid = threadIdx.x;
    if (tid < 128) w_s[tid] = pe_w[tid];
    if (tid < 16) {
        pb_s[tid] = pe_bias[tid]; g_s[tid] = pe_g[tid]; b_s[tid] = pe_b[tid];
        n1g_s[tid] = n1_g[tid]; n1b_s[tid] = n1_b[tid];
    }
    for (int i = tid; i < 768; i += 256) qkvw_s[i] = qkv_w[i];
    __syncthreads();
    const int g = blockIdx.x * 256 + tid;
    if (g >= NTOK) return;
    const int z = g / 2401;
    const int r = g - z * 2401;
    const int y = r / 49;
    const int xx = r - y * 49;
    const float* bp = x + ((2 * z) * 98 + (2 * y)) * 98 + 2 * xx;
    float in[8];
    in[0] = bp[0];    in[1] = bp[1];
    in[2] = bp[98];   in[3] = bp[99];
    in[4] = bp[9604]; in[5] = bp[9605];
    in[6] = bp[9702]; in[7] = bp[9703];
    float v[16];
    float mu = 0.f;
    #pragma unroll
    for (int c = 0; c < 16; ++c) {
        float a = pb_s[c];
        #pragma unroll
        for (int k = 0; k < 8; ++k) a = fmaf(in[k], w_s[c * 8 + k], a);
        v[c] = a; mu += a;
    }
    mu *= 0.0625f;
    float var = 0.f;
    #pragma unroll
    for (int c = 0; c < 16; ++c) { float d = v[c] - mu; var = fmaf(d, d, var); }
    var *= 0.0625f;
    float rs = rsqrtf(var + 1e-5f);
    float o[16];
    #pragma unroll
    for (int c = 0; c < 16; ++c) o[c] = (v[c] - mu) * rs * g_s[c] + b_s[c];

    const int zw = z / 7, zi = z - zw * 7;
    const int yw = y / 7, yi = y - yw * 7;
    const int xw = xx / 7, xi = xx - xw * 7;
    const int w = (zw * 7 + yw) * 7 + xw;
    const int t = (zi * 7 + yi) * 7 + xi;
    const int widx = w * NWTOK + t;

    float4* dst = (float4*)(xe + (size_t)widx * 16);
    dst[0] = ((float4*)o)[0]; dst[1] = ((float4*)o)[1];
    dst[2] = ((float4*)o)[2]; dst[3] = ((float4*)o)[3];

    mu = 0.f;
    #pragma unroll
    for (int c = 0; c < 16; ++c) mu += o[c];
    mu *= 0.0625f;
    var = 0.f;
    #pragma unroll
    for (int c = 0; c < 16; ++c) { float d = o[c] - mu; var = fmaf(d, d, var); }
    var *= 0.0625f;
    rs = rsqrtf(var + 1e-5f);
    float yv[16];
    #pragma unroll
    for (int c = 0; c < 16; ++c) yv[c] = (o[c] - mu) * rs * n1g_s[c] + n1b_s[c];

    float tmp[16];
    #pragma unroll
    for (int rr = 0; rr < 16; ++rr) {
        float a = 0.f;
        #pragma unroll
        for (int c = 0; c < 16; ++c) a = fmaf(yv[c], qkvw_s[rr * 16 + c], a);
        tmp[rr] = a * QSCALE;
    }
    store_f16_row(qg + (size_t)(w * 2) * QPLANE, t, tmp);
    store_f16_row(qg + (size_t)(w * 2 + 1) * QPLANE, t, tmp + 8);
    #pragma unroll
    for (int rr = 0; rr < 16; ++rr) {
        float a = 0.f;
        #pragma unroll
        for (int c = 0; c < 16; ++c) a = fmaf(yv[c], qkvw_s[(16 + rr) * 16 + c], a);
        tmp[rr] = a;
    }
    store_f16_row(kg + (size_t)(w * 2) * QPLANE, t, tmp);
    store_f16_row(kg + (size_t)(w * 2 + 1) * QPLANE, t, tmp + 8);
    #pragma unroll
    for (int rr = 0; rr < 16; ++rr) {
        float a = 0.f;
        #pragma unroll
        for (int c = 0; c < 16; ++c) a = fmaf(yv[c], qkvw_s[(32 + rr) * 16 + c], a);
        tmp[rr] = a;
    }
    store_f16_row(vg + (size_t)(w * 2) * QPLANE, t, tmp);
    store_f16_row(vg + (size_t)(w * 2 + 1) * QPLANE, t, tmp + 8);
}

// ---- K_attn (MFMA): WG per (window,head), 8 waves, 16x16x16 f16 ----
// S^T tile = mfma(A=K, B=Q^T, C=bias); p = exp2(S^T); O^T acc = mfma(A=V^T, B=p).
// D layout (m89): col = lane&15 (query), row = (lane>>4)*4+reg (key) — identical
// (g,reg) slotting to the PV B-operand, so P feeds PV with zero cross-lane moves.
__global__ __launch_bounds__(512, 4) void k_attn(
    const u32* __restrict__ qg,
    const u32* __restrict__ kg,
    const u32* __restrict__ vg,
    float* __restrict__ og,
    const float* __restrict__ bexp)   // this block's [2][352][352], pre-scaled log2e
{
    __shared__ __fp16 Kl[NPAD][16];   // keys x dims (8 real + 8 zero)
    __shared__ __fp16 Ql[NPAD][16];   // queries x dims
    __shared__ __fp16 Vt[16][360];    // dims x keys (padded stride vs bank conflicts)

    const int tid = threadIdx.x;
    const int wh = blockIdx.x;
    const int h = wh & 1;
    const size_t qpl = (size_t)wh * QPLANE;

    if (tid < NPAD) {
        const uint4 z4 = make_uint4(0, 0, 0, 0);
        if (tid < NWTOK) {
            const uint4 kw = ((const uint4*)(kg + qpl))[tid];
            const uint4 qw = ((const uint4*)(qg + qpl))[tid];
            const uint4 vw = ((const uint4*)(vg + qpl))[tid];
            *(uint4*)&Kl[tid][0] = kw; *(uint4*)&Kl[tid][8] = z4;
            *(uint4*)&Ql[tid][0] = qw; *(uint4*)&Ql[tid][8] = z4;
            const h2 v01 = __builtin_bit_cast(h2, vw.x);
            const h2 v23 = __builtin_bit_cast(h2, vw.y);
            const h2 v45 = __builtin_bit_cast(h2, vw.z);
            const h2 v67 = __builtin_bit_cast(h2, vw.w);
            Vt[0][tid] = v01.x; Vt[1][tid] = v01.y;
            Vt[2][tid] = v23.x; Vt[3][tid] = v23.y;
            Vt[4][tid] = v45.x; Vt[5][tid] = v45.y;
            Vt[6][tid] = v67.x; Vt[7][tid] = v67.y;
        } else {
            *(uint4*)&Kl[tid][0] = z4; *(uint4*)&Kl[tid][8] = z4;
            *(uint4*)&Ql[tid][0] = z4; *(uint4*)&Ql[tid][8] = z4;
            #pragma unroll
            for (int d = 0; d < 8; ++d) Vt[d][tid] = (__fp16)0.f;
        }
        #pragma unroll
        for (int d = 8; d < 16; ++d) Vt[d][tid] = (__fp16)0.f;
    }
    __syncthreads();

    const int wave = tid >> 6;
    const int lane = tid & 63;
    const int n = lane & 15;          // query (D col / B col); also key row for A reads
    const int g4 = (lane >> 4) * 4;   // k-group base (keys in D rows / B rows)

    for (int qt = wave; qt < 22; qt += 8) {
        const int qi = qt * 16 + n;
        const h4 bq = *(const h4*)&Ql[qi][g4];            // B = Q^T frag, fixed per qt
        const float* brow = bexp + ((size_t)h * NPAD + qi) * NPAD;
        f32x4 acc = {0.f, 0.f, 0.f, 0.f};
        float l = 0.f;
        for (int kt = 0; kt < 22; ++kt) {
            const f32x4 cb = *(const f32x4*)(brow + kt * 16 + g4);      // bias -> C
            const h4 ak = *(const h4*)&Kl[kt * 16 + n][g4];             // A = K rows
            f32x4 s = __builtin_amdgcn_mfma_f32_16x16x16f16(ak, bq, cb, 0, 0, 0);
            const float p0 = fast_exp2(s[0]);
            const float p1 = fast_exp2(s[1]);
            const float p2 = fast_exp2(s[2]);
            const float p3 = fast_exp2(s[3]);
            l += (p0 + p1) + (p2 + p3);
            const u32 lo = packh2(p0, p1);
            const u32 hi = packh2(p2, p3);
            const h4 bp = __builtin_bit_cast(h4, make_uint2(lo, hi));   // B = P^T frag
            const h4 av = *(const h4*)&Vt[n][kt * 16 + g4];             // A = V^T rows
            acc = __builtin_amdgcn_mfma_f32_16x16x16f16(av, bp, acc, 0, 0, 0);
        }
        l += __shfl_xor(l, 16);
        l += __shfl_xor(l, 32);
        if (g4 < 8 && qi < NWTOK) {   // g in {0,1} hold real dims 0..7
            const float inv = 1.f / l;
            f32x4 o = acc * inv;
            *(f32x4*)(og + (size_t)wh * OPLANE + qi * 8 + g4) = o;
        }
    }
}

// ------- K_post: proj + residual + LN2 + MLP (+ next LN1+QKV or output) -------
__global__ __launch_bounds__(256, 2) void k_post(
    float* __restrict__ xe,
    const float* __restrict__ og,
    u32* __restrict__ qg,
    u32* __restrict__ kg,
    u32* __restrict__ vg,
    const float* __restrict__ proj_w,
    const float* __restrict__ proj_b,
    const float* __restrict__ n2_g,
    const float* __restrict__ n2_b,
    const float* __restrict__ fc1_w,
    const float* __restrict__ fc1_b,
    const float* __restrict__ fc2_w,
    const float* __restrict__ fc2_b,
    const float* __restrict__ n1_g_nx,
    const float* __restrict__ n1_b_nx,
    const float* __restrict__ qkv_w_nx,
    float* __restrict__ outp,
    const int last)
{
    __shared__ float projw_s[256];
    __shared__ float fc1w_s[1024];
    __shared__ float fc2w_s[1024];
    __shared__ float qkvw_s[768];
    __shared__ float projb_s[16], n2g_s[16], n2b_s[16], fc2b_s[16], n1g_s[16], n1b_s[16];
    __shared__ float fc1b_s[64];
    const int tid = threadIdx.x;
    if (tid < 256) projw_s[tid] = proj_w[tid];
    for (int i = tid; i < 1024; i += 256) { fc1w_s[i] = fc1_w[i]; fc2w_s[i] = fc2_w[i]; }
    for (int i = tid; i < 768; i += 256) qkvw_s[i] = qkv_w_nx[i];
    if (tid < 16) {
        projb_s[tid] = proj_b[tid];
        n2g_s[tid] = n2_g[tid]; n2b_s[tid] = n2_b[tid];
        fc2b_s[tid] = fc2_b[tid];
        n1g_s[tid] = n1_g_nx[tid]; n1b_s[tid] = n1_b_nx[tid];
    }
    if (tid < 64) fc1b_s[tid] = fc1_b[tid];
    __syncthreads();

    const int widx = blockIdx.x * 256 + tid;
    if (widx >= NTOK) return;
    const int w = widx / NWTOK;
    const int t = widx - w * NWTOK;

    float o[16];
    const float* o0 = og + (size_t)(w * 2) * OPLANE + t * 8;
    const float* o1 = og + (size_t)(w * 2 + 1) * OPLANE + t * 8;
    ((float4*)o)[0] = ((const float4*)o0)[0]; ((float4*)o)[1] = ((const float4*)o0)[1];
    ((float4*)o)[2] = ((const float4*)o1)[0]; ((float4*)o)[3] = ((const float4*)o1)[1];

    float xr[16];
    const float4* xs = (const float4*)(xe + (size_t)widx * 16);
    ((float4*)xr)[0] = xs[0]; ((float4*)xr)[1] = xs[1];
    ((float4*)xr)[2] = xs[2]; ((float4*)xr)[3] = xs[3];

    #pragma unroll
    for (int c = 0; c < 16; ++c) {
        float a = projb_s[c];
        #pragma unroll
        for (int cc = 0; cc < 16; ++cc) a = fmaf(o[cc], projw_s[c * 16 + cc], a);
        xr[c] += a;
    }

    float mu = 0.f;
    #pragma unroll
    for (int c = 0; c < 16; ++c) mu += xr[c];
    mu *= 0.0625f;
    float var = 0.f;
    #pragma unroll
    for (int c = 0; c < 16; ++c) { float d = xr[c] - mu; var = fmaf(d, d, var); }
    var *= 0.0625f;
    float rs = rsqrtf(var + 1e-5f);
    float zv[16];
    #pragma unroll
    for (int c = 0; c < 16; ++c) zv[c] = (xr[c] - mu) * rs * n2g_s[c] + n2b_s[c];

    float accm[16];
    #pragma unroll
    for (int c = 0; c < 16; ++c) accm[c] = fc2b_s[c];
    #pragma unroll
    for (int ch = 0; ch < 4; ++ch) {
        float hv[16];
        #pragma unroll
        for (int mm = 0; mm < 16; ++mm) {
            const int mi = ch * 16 + mm;
            float a = fc1b_s[mi];
            #pragma unroll
            for (int c = 0; c < 16; ++c) a = fmaf(zv[c], fc1w_s[mi * 16 + c], a);
            hv[mm] = gelu_exact(a);
        }
        #pragma unroll
        for (int c = 0; c < 16; ++c) {
            float a = accm[c];
            #pragma unroll
            for (int mm = 0; mm < 16; ++mm) a = fmaf(hv[mm], fc2w_s[c * 64 + ch * 16 + mm], a);
            accm[c] = a;
        }
    }
    #pragma unroll
    for (int c = 0; c < 16; ++c) xr[c] += accm[c];

    if (last) {
        const int wd = w / 49;
        const int wr2 = w - wd * 49;
        const int whh = wr2 / 7;
        const int www = wr2 - whh * 7;
        const int tz = t / 49;
        const int tr2 = t - tz * 49;
        const int ty = tr2 / 7;
        const int tx = tr2 - ty * 7;
        const int g = ((wd * 7 + tz) * 49 + (whh * 7 + ty)) * 49 + (www * 7 + tx);
        #pragma unroll
        for (int c = 0; c < 16; ++c) outp[(size_t)c * NTOK + g] = xr[c];
        return;
    }

    float4* dst = (float4*)(xe + (size_t)widx * 16);
    dst[0] = ((float4*)xr)[0]; dst[1] = ((float4*)xr)[1];
    dst[2] = ((float4*)xr)[2]; dst[3] = ((float4*)xr)[3];

    // LN1 + QKV for next block (f16 packed)
    mu = 0.f;
    #pragma unroll
    for (int c = 0; c < 16; ++c) mu += xr[c];
    mu *= 0.0625f;
    var = 0.f;
    #pragma unroll
    for (int c = 0; c < 16; ++c) { float d = xr[c] - mu; var = fmaf(d, d, var); }
    var *= 0.0625f;
    rs = rsqrtf(var + 1e-5f);
    float yv[16];
    #pragma unroll
    for (int c = 0; c < 16; ++c) yv[c] = (xr[c] - mu) * rs * n1g_s[c] + n1b_s[c];

    float tmp[16];
    #pragma unroll
    for (int rr = 0; rr < 16; ++rr) {
        float a = 0.f;
        #pragma unroll
        for (int c = 0; c < 16; ++c) a = fmaf(yv[c], qkvw_s[rr * 16 + c], a);
        tmp[rr] = a * QSCALE;
    }
    store_f16_row(qg + (size_t)(w * 2) * QPLANE, t, tmp);
    store_f16_row(qg + (size_t)(w * 2 + 1) * QPLANE, t, tmp + 8);
    #pragma unroll
    for (int rr = 0; rr < 16; ++rr) {
        float a = 0.f;
        #pragma unroll
        for (int c = 0; c < 16; ++c) a = fmaf(yv[c], qkvw_s[(16 + rr) * 16 + c], a);
        tmp[rr] = a;
    }
    store_f16_row(kg + (size_t)(w * 2) * QPLANE, t, tmp);
    store_f16_row(kg + (size_t)(w * 2 + 1) * QPLANE, t, tmp + 8);
    #pragma unroll
    for (int rr = 0; rr < 16; ++rr) {
        float a = 0.f;
        #pragma unroll
        for (int c = 0; c < 16; ++c) a = fmaf(yv[c], qkvw_s[(32 + rr) * 16 + c], a);
        tmp[rr] = a;
    }
    store_f16_row(vg + (size_t)(w * 2) * QPLANE, t, tmp);
    store_f16_row(vg + (size_t)(w * 2 + 1) * QPLANE, t, tmp + 8);
}

extern "C" void kernel_launch(void* const* d_in, const int* in_sizes, int n_in,
                              void* d_out, int out_size, void* d_ws, size_t ws_size,
                              hipStream_t stream) {
    const float* x       = (const float*)d_in[0];
    const float* pe_w    = (const float*)d_in[1];
    const float* pe_bias = (const float*)d_in[2];
    const float* pe_g    = (const float*)d_in[3];
    const float* pe_b    = (const float*)d_in[4];
    const float* n1_g    = (const float*)d_in[5];
    const float* n1_b    = (const float*)d_in[6];
    const float* qkv_w   = (const float*)d_in[7];
    const float* rpb     = (const float*)d_in[8];
    const float* proj_w  = (const float*)d_in[9];
    const float* proj_b  = (const float*)d_in[10];
    const float* n2_g    = (const float*)d_in[11];
    const float* n2_b    = (const float*)d_in[12];
    const float* fc1_w   = (const float*)d_in[13];
    const float* fc1_b   = (const float*)d_in[14];
    const float* fc2_w   = (const float*)d_in[15];
    const float* fc2_b   = (const float*)d_in[16];

    float* ws = (float*)d_ws;
    const size_t SEG = (size_t)NTOK * 16;     // 1,882,384 floats
    const size_t QSEG = (size_t)686 * QPLANE; // 941,192 u32
    float* xe = ws;
    u32* qg = (u32*)(ws + SEG);
    u32* kg = qg + QSEG;
    u32* vg = kg + QSEG;
    float* og = (float*)(vg + QSEG);                  // 686*2744 f32
    float* bexp = og + (size_t)686 * OPLANE;          // 6*352*352 f32
    float* out = (float*)d_out;

    k_bias_expand<<<6 * NPAD, 384, 0, stream>>>(rpb, bexp);

    k0_patch_qkv<<<(NTOK + 255) / 256, 256, 0, stream>>>(
        x, pe_w, pe_bias, pe_g, pe_b, n1_g, n1_b, qkv_w, xe, qg, kg, vg);

    for (int i = 0; i < 3; ++i) {
        const int last = (i == 2) ? 1 : 0;
        const int nx = last ? i : i + 1;
        k_attn<<<686, 512, 0, stream>>>(
            qg, kg, vg, og, bexp + (size_t)i * 2 * NPAD * NPAD);
        k_post<<<(NTOK + 255) / 256, 256, 0, stream>>>(
            xe, og, qg, kg, vg,
            proj_w + (size_t)i * 256, proj_b + (size_t)i * 16,
            n2_g + (size_t)i * 16, n2_b + (size_t)i * 16,
            fc1_w + (size_t)i * 1024, fc1_b + (size_t)i * 64,
            fc2_w + (size_t)i * 1024, fc2_b + (size_t)i * 16,
            n1_g + (size_t)nx * 16, n1_b + (size_t)nx * 16,
            qkv_w + (size_t)nx * 768,
            out, last);
    }
}